// Round 9
// baseline (591.599 us; speedup 1.0000x reference)
//
#include <hip/hip_runtime.h>

// ---------------------------------------------------------------------------
// 3-layer GCN: out = ReLU(Â(ReLU(Â(Â (X W1^T) +b1) W2^T +b2)) W3^T) +b3
// Â = D^{-1/2}(A+I)D^{-1/2}, deg = in-degree + 1 (self loop).
// Pipeline (R9):
//   gemm1:    xs1 = dinv*(X W1^T)            (bf16 [N][128])
//   agg_gemm: h = ReLU(Â-combine(xs1)+b1); xs2 = dinv*(h W2^T)   (fused!)
//   agg_gemm: h = ReLU(Â-combine(xs2)+b2); xs3 = dinv*(h W3^T)
//   aggregate2: out = Â-combine(xs3)+b3      (f32 d_out)
// R8 pm: aggregate is L2-fill-BW bound (~3.75 TB/s random lines, invariant
// across f32/bf16/4xMLP variants; FETCH 188MB ~ structural floor for uniform
// random src with per-XCD L2). So R9 removes everything that ISN'T the gather
// from the critical path: fuse agg epilogue -> hi/lo bf16 LDS planes -> MFMA
// (kills 50MB agg-write + 51MB gemm-read + gemm split-VALU per boundary).
// bin_edges grid 128->512 WGs (was using half the CUs).
// ---------------------------------------------------------------------------

#define NPB 256          // nodes per bucket (bucket = dst >> 8)
#define CAP 4672         // edges capacity per bucket region
#define BIN_WGS 512      // workgroups in bin_edges

typedef short bfrag __attribute__((ext_vector_type(8)));       // 8 bf16
typedef float f32x4 __attribute__((ext_vector_type(4)));
typedef unsigned short u16x8 __attribute__((ext_vector_type(8)));

__global__ __launch_bounds__(256) void init_cur(int* __restrict__ cur, int B) {
  int i = blockIdx.x * 256 + threadIdx.x;
  if (i < B) cur[i] = i * CAP;
}

__global__ __launch_bounds__(256) void bin_edges(const int* __restrict__ src,
                                                 const int* __restrict__ dst,
                                                 int* __restrict__ cur,
                                                 int* __restrict__ binned,
                                                 int E, int B) {
  __shared__ int lc[512];
  __shared__ int lbase[512];
  const int t = threadIdx.x;
  const int chunk = (E + BIN_WGS - 1) / BIN_WGS;
  const int e0 = blockIdx.x * chunk;
  const int e1 = min(E, e0 + chunk);

  for (int i = t; i < B; i += 256) lc[i] = 0;
  __syncthreads();
  for (int e = e0 + t; e < e1; e += 256) {
    int d = dst[e];
    atomicAdd(&lc[d >> 8], 1);
  }
  __syncthreads();
  for (int i = t; i < B; i += 256) {
    int c = lc[i];
    lbase[i] = c ? atomicAdd(&cur[i], c) : 0;
    lc[i] = 0;
  }
  __syncthreads();
  for (int e = e0 + t; e < e1; e += 256) {
    int d = dst[e];
    int s = __builtin_nontemporal_load(&src[e]);
    int bk = d >> 8;
    int p = lbase[bk] + atomicAdd(&lc[bk], 1);
    if (p < (bk + 1) * CAP)
      binned[p] = ((d & 255) << 24) | s;
  }
}

__global__ __launch_bounds__(256) void build_buckets(const int* __restrict__ binned,
                                                     const int* __restrict__ cur,
                                                     int* __restrict__ cols,
                                                     int2* __restrict__ off2,
                                                     float* __restrict__ dinv,
                                                     int N) {
  __shared__ int eb[CAP];
  __shared__ int ob[CAP];
  __shared__ int lc[256];
  __shared__ int sc[256];
  const int b = blockIdx.x;
  const int t = threadIdx.x;
  const int base = b * CAP;
  const int cntb = min(cur[b] - base, CAP);

  for (int i = t; i < cntb; i += 256) eb[i] = binned[base + i];
  lc[t] = 0;
  __syncthreads();
  for (int i = t; i < cntb; i += 256)
    atomicAdd(&lc[(unsigned)eb[i] >> 24], 1);
  __syncthreads();
  int myc = lc[t];
  sc[t] = myc;
  __syncthreads();
  for (int d = 1; d < 256; d <<= 1) {
    int a = (t >= d) ? sc[t - d] : 0;
    __syncthreads();
    sc[t] += a;
    __syncthreads();
  }
  int excl = sc[t] - myc;
  int node = b * NPB + t;
  if (node < N) {
    off2[node] = make_int2(base + excl, base + excl + myc);
    dinv[node] = rsqrtf((float)(myc + 1));
  }
  lc[t] = excl;
  __syncthreads();
  for (int i = t; i < cntb; i += 256) {
    int e = eb[i];
    int p = atomicAdd(&lc[(unsigned)e >> 24], 1);
    ob[p] = e & 0xFFFFFF;
  }
  __syncthreads();
  for (int i = t; i < cntb; i += 256) cols[base + i] = ob[i];
}

// ---------------------------------------------------------------------------
__device__ inline unsigned short bf16rne(float x) {
  unsigned u = __float_as_uint(x);
  return (unsigned short)((u + 0x7FFFu + ((u >> 16) & 1u)) >> 16);
}
__device__ inline float bf16lo(unsigned q) { return __uint_as_float(q << 16); }
__device__ inline float bf16hi(unsigned q) { return __uint_as_float(q & 0xFFFF0000u); }

// W -> hi/lo bf16 planes, once per layer
__global__ __launch_bounds__(256) void split_w(const float* __restrict__ W,
                                               unsigned short* __restrict__ hi,
                                               unsigned short* __restrict__ lo,
                                               int total) {
  int i = blockIdx.x * 256 + threadIdx.x;
  if (i < total) {
    float v = W[i];
    unsigned short h = bf16rne(v);
    hi[i] = h;
    lo[i] = bf16rne(v - __uint_as_float((unsigned)h << 16));
  }
}

// ---------------------------------------------------------------------------
// Layer-1 GEMM: Y[m][c] = bf16( dinv[m] * dot(X[m][:], W[c][:]) ), split-bf16
// (xh*wh + xl*wh + xh*wl), X staged f32->hi/lo planes, W planes from global.
// ---------------------------------------------------------------------------
#define LDP 136  // padded LDS row stride (bf16 elems): 2-way bank alias only
template <int OUTC>
__global__ __launch_bounds__(256) void gemm_xw_mfma(const float* __restrict__ X,
                                                    const unsigned short* __restrict__ Whg,
                                                    const unsigned short* __restrict__ Wlg,
                                                    const float* __restrict__ dinv,
                                                    unsigned short* __restrict__ Y,
                                                    int M) {
  __shared__ unsigned short Xhi[64 * LDP], Xlo[64 * LDP];
  __shared__ unsigned short Whi[64 * LDP], Wlo[64 * LDP];
  const int tid = threadIdx.x;
  const int m_base = blockIdx.x * 64;

  for (int idx = tid; idx < 64 * 16; idx += 256) {
    int r = idx >> 4, g = idx & 15;
    int m = m_base + r;
    float4 v0 = make_float4(0.f, 0.f, 0.f, 0.f), v1 = v0;
    if (m < M) {
      const float4* px = (const float4*)(X + (size_t)m * 128 + g * 8);
      v0 = px[0];
      v1 = px[1];
    }
    float vv[8] = {v0.x, v0.y, v0.z, v0.w, v1.x, v1.y, v1.z, v1.w};
    u16x8 hv, lv;
#pragma unroll
    for (int j = 0; j < 8; ++j) {
      unsigned short h = bf16rne(vv[j]);
      float res = vv[j] - __uint_as_float((unsigned)h << 16);
      hv[j] = h;
      lv[j] = bf16rne(res);
    }
    *(u16x8*)(Xhi + r * LDP + g * 8) = hv;
    *(u16x8*)(Xlo + r * LDP + g * 8) = lv;
  }

  const int lane = tid & 63;
  const int wv = tid >> 6;
  const int col_l = lane & 15;
  const int quad = lane >> 4;
  const int aBase = (wv * 16 + col_l) * LDP + quad * 8;
  const int bBase = col_l * LDP + quad * 8;

  for (int cc = 0; cc < OUTC; cc += 64) {
    __syncthreads();
    for (int idx = tid; idx < 64 * 16; idx += 256) {
      int r = idx >> 4, g = idx & 15;
      u16x8 hv = *(const u16x8*)(Whg + (size_t)(cc + r) * 128 + g * 8);
      u16x8 lv = *(const u16x8*)(Wlg + (size_t)(cc + r) * 128 + g * 8);
      *(u16x8*)(Whi + r * LDP + g * 8) = hv;
      *(u16x8*)(Wlo + r * LDP + g * 8) = lv;
    }
    __syncthreads();

    f32x4 acc[4] = {{0.f, 0.f, 0.f, 0.f},
                    {0.f, 0.f, 0.f, 0.f},
                    {0.f, 0.f, 0.f, 0.f},
                    {0.f, 0.f, 0.f, 0.f}};
#pragma unroll
    for (int ks = 0; ks < 4; ++ks) {
      int ao = aBase + ks * 32;
      bfrag aHi = *(const bfrag*)(Xhi + ao);
      bfrag aLo = *(const bfrag*)(Xlo + ao);
#pragma unroll
      for (int t = 0; t < 4; ++t) {
        int bo = bBase + t * 16 * LDP + ks * 32;
        bfrag bHi = *(const bfrag*)(Whi + bo);
        bfrag bLo = *(const bfrag*)(Wlo + bo);
        acc[t] = __builtin_amdgcn_mfma_f32_16x16x32_bf16(aHi, bHi, acc[t], 0, 0, 0);
        acc[t] = __builtin_amdgcn_mfma_f32_16x16x32_bf16(aLo, bHi, acc[t], 0, 0, 0);
        acc[t] = __builtin_amdgcn_mfma_f32_16x16x32_bf16(aHi, bLo, acc[t], 0, 0, 0);
      }
    }

#pragma unroll
    for (int r = 0; r < 4; ++r) {
      int row = m_base + wv * 16 + quad * 4 + r;
      if (row < M) {
        float s = dinv[row];
#pragma unroll
        for (int t = 0; t < 4; ++t) {
          unsigned short h = bf16rne(acc[t][r] * s);
          Y[(size_t)row * OUTC + cc + t * 16 + col_l] = h;
        }
      }
    }
  }
}

// ---------------------------------------------------------------------------
// Fused aggregate+GEMM (R9). Block owns 64 dst nodes. Phase 1: wave wv
// aggregates its 16 gemm-rows sequentially (gather xs bf16 [N][128], lane =
// (eg,cg) as aggregate2), epilogue h=ReLU(dinv*sum+bias) split to hi/lo bf16
// LDS planes. Phase 2: MFMA from LDS, xs_next = bf16(dinv*(h W^T)) to global.
// ---------------------------------------------------------------------------
template <int OUTC, bool RELU>
__global__ __launch_bounds__(256) void agg_gemm(const unsigned short* __restrict__ xs,
                                                const int2* __restrict__ off2,
                                                const int* __restrict__ cols,
                                                const float* __restrict__ dinv,
                                                const float* __restrict__ bias,
                                                const unsigned short* __restrict__ Whg,
                                                const unsigned short* __restrict__ Wlg,
                                                unsigned short* __restrict__ Y,
                                                int N) {
  __shared__ unsigned short Xhi[64 * LDP], Xlo[64 * LDP];
  __shared__ unsigned short Whi[64 * LDP], Wlo[64 * LDP];
  const int tid = threadIdx.x;
  const int lane = tid & 63;
  const int wv = tid >> 6;
  const int eg = lane >> 4;   // edge subgroup (4)
  const int cg = lane & 15;   // channel group (16 x 8ch)
  const int m_base = blockIdx.x * 64;

  // ---- phase 1: aggregate 16 nodes per wave into LDS hi/lo planes ----
  for (int r = 0; r < 16; ++r) {
    const int row = wv * 16 + r;
    const int wid = m_base + row;
    float acc[8] = {0.f, 0.f, 0.f, 0.f, 0.f, 0.f, 0.f, 0.f};
    if (wid < N) {
      if (eg == 0) {  // self term counted once
        uint4 d = *(const uint4*)(xs + (size_t)wid * 128 + cg * 8);
        acc[0] = bf16lo(d.x); acc[1] = bf16hi(d.x);
        acc[2] = bf16lo(d.y); acc[3] = bf16hi(d.y);
        acc[4] = bf16lo(d.z); acc[5] = bf16hi(d.z);
        acc[6] = bf16lo(d.w); acc[7] = bf16hi(d.w);
      }
      int2 oo = off2[wid];
      int ebase = oo.x;
      const int eend = oo.y;
      while (ebase < eend) {
        int cnt = eend - ebase;
        if (cnt > 64) cnt = 64;
        int col = (lane < cnt) ? __builtin_nontemporal_load(&cols[ebase + lane]) : 0;
        const int c1 = cnt - 1;
        for (int j = 0; j < cnt; j += 16) {
          int i0 = j + eg, i1 = i0 + 4, i2 = i1 + 4, i3 = i2 + 4;
          int s0 = __shfl(col, min(i0, c1));
          int s1 = __shfl(col, min(i1, c1));
          int s2 = __shfl(col, min(i2, c1));
          int s3 = __shfl(col, min(i3, c1));
          uint4 d0 = *(const uint4*)(xs + (size_t)s0 * 128 + cg * 8);
          uint4 d1 = *(const uint4*)(xs + (size_t)s1 * 128 + cg * 8);
          uint4 d2 = *(const uint4*)(xs + (size_t)s2 * 128 + cg * 8);
          uint4 d3 = *(const uint4*)(xs + (size_t)s3 * 128 + cg * 8);
          if (i0 < cnt) {
            acc[0] += bf16lo(d0.x); acc[1] += bf16hi(d0.x);
            acc[2] += bf16lo(d0.y); acc[3] += bf16hi(d0.y);
            acc[4] += bf16lo(d0.z); acc[5] += bf16hi(d0.z);
            acc[6] += bf16lo(d0.w); acc[7] += bf16hi(d0.w);
          }
          if (i1 < cnt) {
            acc[0] += bf16lo(d1.x); acc[1] += bf16hi(d1.x);
            acc[2] += bf16lo(d1.y); acc[3] += bf16hi(d1.y);
            acc[4] += bf16lo(d1.z); acc[5] += bf16hi(d1.z);
            acc[6] += bf16lo(d1.w); acc[7] += bf16hi(d1.w);
          }
          if (i2 < cnt) {
            acc[0] += bf16lo(d2.x); acc[1] += bf16hi(d2.x);
            acc[2] += bf16lo(d2.y); acc[3] += bf16hi(d2.y);
            acc[4] += bf16lo(d2.z); acc[5] += bf16hi(d2.z);
            acc[6] += bf16lo(d2.w); acc[7] += bf16hi(d2.w);
          }
          if (i3 < cnt) {
            acc[0] += bf16lo(d3.x); acc[1] += bf16hi(d3.x);
            acc[2] += bf16lo(d3.y); acc[3] += bf16hi(d3.y);
            acc[4] += bf16lo(d3.z); acc[5] += bf16hi(d3.z);
            acc[6] += bf16lo(d3.w); acc[7] += bf16hi(d3.w);
          }
        }
        ebase += cnt;
      }
#pragma unroll
      for (int m = 16; m < 64; m <<= 1) {
#pragma unroll
        for (int q = 0; q < 8; ++q) acc[q] += __shfl_xor(acc[q], m);
      }
      if (eg == 0) {
        float dd = dinv[wid];
        const float4 bA = *(const float4*)(bias + cg * 8);
        const float4 bB = *(const float4*)(bias + cg * 8 + 4);
        float h[8];
        h[0] = acc[0] * dd + bA.x; h[1] = acc[1] * dd + bA.y;
        h[2] = acc[2] * dd + bA.z; h[3] = acc[3] * dd + bA.w;
        h[4] = acc[4] * dd + bB.x; h[5] = acc[5] * dd + bB.y;
        h[6] = acc[6] * dd + bB.z; h[7] = acc[7] * dd + bB.w;
        u16x8 hv, lv;
#pragma unroll
        for (int q = 0; q < 8; ++q) {
          float v = RELU ? fmaxf(h[q], 0.f) : h[q];
          unsigned short hb = bf16rne(v);
          hv[q] = hb;
          lv[q] = bf16rne(v - __uint_as_float((unsigned)hb << 16));
        }
        *(u16x8*)(Xhi + row * LDP + cg * 8) = hv;
        *(u16x8*)(Xlo + row * LDP + cg * 8) = lv;
      }
    } else if (eg == 0) {
      u16x8 z = {0, 0, 0, 0, 0, 0, 0, 0};
      *(u16x8*)(Xhi + row * LDP + cg * 8) = z;
      *(u16x8*)(Xlo + row * LDP + cg * 8) = z;
    }
  }

  // ---- phase 2: GEMM from LDS planes ----
  const int col_l = cg;
  const int quad = eg;
  const int aBase = (wv * 16 + col_l) * LDP + quad * 8;
  const int bBase = col_l * LDP + quad * 8;

  for (int cc = 0; cc < OUTC; cc += 64) {
    __syncthreads();  // phase-1 planes ready / previous W consumed
    for (int idx = tid; idx < 64 * 16; idx += 256) {
      int r = idx >> 4, g = idx & 15;
      u16x8 hv = *(const u16x8*)(Whg + (size_t)(cc + r) * 128 + g * 8);
      u16x8 lv = *(const u16x8*)(Wlg + (size_t)(cc + r) * 128 + g * 8);
      *(u16x8*)(Whi + r * LDP + g * 8) = hv;
      *(u16x8*)(Wlo + r * LDP + g * 8) = lv;
    }
    __syncthreads();

    f32x4 acc4[4] = {{0.f, 0.f, 0.f, 0.f},
                     {0.f, 0.f, 0.f, 0.f},
                     {0.f, 0.f, 0.f, 0.f},
                     {0.f, 0.f, 0.f, 0.f}};
#pragma unroll
    for (int ks = 0; ks < 4; ++ks) {
      int ao = aBase + ks * 32;
      bfrag aHi = *(const bfrag*)(Xhi + ao);
      bfrag aLo = *(const bfrag*)(Xlo + ao);
#pragma unroll
      for (int t = 0; t < 4; ++t) {
        int bo = bBase + t * 16 * LDP + ks * 32;
        bfrag bHi = *(const bfrag*)(Whi + bo);
        bfrag bLo = *(const bfrag*)(Wlo + bo);
        acc4[t] = __builtin_amdgcn_mfma_f32_16x16x32_bf16(aHi, bHi, acc4[t], 0, 0, 0);
        acc4[t] = __builtin_amdgcn_mfma_f32_16x16x32_bf16(aLo, bHi, acc4[t], 0, 0, 0);
        acc4[t] = __builtin_amdgcn_mfma_f32_16x16x32_bf16(aHi, bLo, acc4[t], 0, 0, 0);
      }
    }

#pragma unroll
    for (int r = 0; r < 4; ++r) {
      int row = m_base + wv * 16 + quad * 4 + r;
      if (row < N) {
        float s = dinv[row];
#pragma unroll
        for (int t = 0; t < 4; ++t) {
          unsigned short h = bf16rne(acc4[t][r] * s);
          Y[(size_t)row * OUTC + cc + t * 16 + col_l] = h;
        }
      }
    }
  }
}

// ---------------------------------------------------------------------------
// Standalone aggregate (final layer): xs bf16 [N][C] -> f32 out + bias.
// ---------------------------------------------------------------------------
template <int C, bool RELU>
__global__ __launch_bounds__(256) void aggregate2(const unsigned short* __restrict__ xs,
                                                  const int2* __restrict__ off2,
                                                  const int* __restrict__ cols,
                                                  const float* __restrict__ dinv,
                                                  const float* __restrict__ bias,
                                                  float* __restrict__ out, int N) {
  constexpr int CG = C / 8;
  constexpr int EG = 64 / CG;
  int wid = (int)((blockIdx.x * blockDim.x + threadIdx.x) >> 6);
  int lane = threadIdx.x & 63;
  if (wid >= N) return;
  const int eg = lane / CG;
  const int cg = lane % CG;

  float acc[8] = {0.f, 0.f, 0.f, 0.f, 0.f, 0.f, 0.f, 0.f};
  if (eg == 0) {
    uint4 d = *(const uint4*)(xs + (size_t)wid * C + cg * 8);
    acc[0] = bf16lo(d.x); acc[1] = bf16hi(d.x);
    acc[2] = bf16lo(d.y); acc[3] = bf16hi(d.y);
    acc[4] = bf16lo(d.z); acc[5] = bf16hi(d.z);
    acc[6] = bf16lo(d.w); acc[7] = bf16hi(d.w);
  }

  int2 oo = off2[wid];
  int ebase = oo.x;
  const int eend = oo.y;
  while (ebase < eend) {
    int cnt = eend - ebase;
    if (cnt > 64) cnt = 64;
    int col = (lane < cnt) ? __builtin_nontemporal_load(&cols[ebase + lane]) : 0;
    const int c1 = cnt - 1;
    for (int j = 0; j < cnt; j += 4 * EG) {
      int i0 = j + eg, i1 = i0 + EG, i2 = i1 + EG, i3 = i2 + EG;
      int s0 = __shfl(col, min(i0, c1));
      int s1 = __shfl(col, min(i1, c1));
      int s2 = __shfl(col, min(i2, c1));
      int s3 = __shfl(col, min(i3, c1));
      uint4 d0 = *(const uint4*)(xs + (size_t)s0 * C + cg * 8);
      uint4 d1 = *(const uint4*)(xs + (size_t)s1 * C + cg * 8);
      uint4 d2 = *(const uint4*)(xs + (size_t)s2 * C + cg * 8);
      uint4 d3 = *(const uint4*)(xs + (size_t)s3 * C + cg * 8);
      if (i0 < cnt) {
        acc[0] += bf16lo(d0.x); acc[1] += bf16hi(d0.x);
        acc[2] += bf16lo(d0.y); acc[3] += bf16hi(d0.y);
        acc[4] += bf16lo(d0.z); acc[5] += bf16hi(d0.z);
        acc[6] += bf16lo(d0.w); acc[7] += bf16hi(d0.w);
      }
      if (i1 < cnt) {
        acc[0] += bf16lo(d1.x); acc[1] += bf16hi(d1.x);
        acc[2] += bf16lo(d1.y); acc[3] += bf16hi(d1.y);
        acc[4] += bf16lo(d1.z); acc[5] += bf16hi(d1.z);
        acc[6] += bf16lo(d1.w); acc[7] += bf16hi(d1.w);
      }
      if (i2 < cnt) {
        acc[0] += bf16lo(d2.x); acc[1] += bf16hi(d2.x);
        acc[2] += bf16lo(d2.y); acc[3] += bf16hi(d2.y);
        acc[4] += bf16lo(d2.z); acc[5] += bf16hi(d2.z);
        acc[6] += bf16lo(d2.w); acc[7] += bf16hi(d2.w);
      }
      if (i3 < cnt) {
        acc[0] += bf16lo(d3.x); acc[1] += bf16hi(d3.x);
        acc[2] += bf16lo(d3.y); acc[3] += bf16hi(d3.y);
        acc[4] += bf16lo(d3.z); acc[5] += bf16hi(d3.z);
        acc[6] += bf16lo(d3.w); acc[7] += bf16hi(d3.w);
      }
    }
    ebase += cnt;
  }

#pragma unroll
  for (int m = CG; m < 64; m <<= 1) {
#pragma unroll
    for (int q = 0; q < 8; ++q) acc[q] += __shfl_xor(acc[q], m);
  }

  if (eg == 0) {
    float dd = dinv[wid];
    const float4 bA = *(const float4*)(bias + cg * 8);
    const float4 bB = *(const float4*)(bias + cg * 8 + 4);
    f32x4 oA, oB;
    oA[0] = acc[0] * dd + bA.x; oA[1] = acc[1] * dd + bA.y;
    oA[2] = acc[2] * dd + bA.z; oA[3] = acc[3] * dd + bA.w;
    oB[0] = acc[4] * dd + bB.x; oB[1] = acc[5] * dd + bB.y;
    oB[2] = acc[6] * dd + bB.z; oB[3] = acc[7] * dd + bB.w;
    if (RELU) {
#pragma unroll
      for (int q = 0; q < 4; ++q) {
        oA[q] = fmaxf(oA[q], 0.f);
        oB[q] = fmaxf(oB[q], 0.f);
      }
    }
    __builtin_nontemporal_store(oA, (f32x4*)(out + (size_t)wid * C + cg * 8));
    __builtin_nontemporal_store(oB, (f32x4*)(out + (size_t)wid * C + cg * 8 + 4));
  }
}

// ---------------------------------------------------------------------------

extern "C" void kernel_launch(void* const* d_in, const int* in_sizes, int n_in,
                              void* d_out, int out_size, void* d_ws, size_t ws_size,
                              hipStream_t stream) {
  const float* x  = (const float*)d_in[0];
  const int*   ei = (const int*)d_in[1];
  const float* W1 = (const float*)d_in[2];
  const float* b1 = (const float*)d_in[3];
  const float* W2 = (const float*)d_in[4];
  const float* b2 = (const float*)d_in[5];
  const float* W3 = (const float*)d_in[6];
  const float* b3 = (const float*)d_in[7];

  const int N = in_sizes[0] / 128;
  const int E = in_sizes[1] / 2;
  const int* src = ei;
  const int* dst = ei + E;
  const int B = (N + NPB - 1) / NPB;

  char* w = (char*)d_ws;
  size_t p = 0;
  auto alloc = [&](size_t bytes) -> void* {
    void* r = w + p;
    p = (p + bytes + 255) & ~(size_t)255;
    return r;
  };
  float*    dinv   = (float*)alloc((size_t)N * 4);
  int2*     off2   = (int2*)alloc((size_t)N * 8);
  int*      cur    = (int*)alloc((size_t)B * 4);
  int*      binned = (int*)alloc((size_t)B * CAP * 4);
  int*      cols   = (int*)alloc((size_t)B * CAP * 4);
  unsigned short* xs1 = (unsigned short*)alloc((size_t)N * 128 * 2);
  unsigned short* xs2 = (unsigned short*)alloc((size_t)N * 128 * 2);
  unsigned short* xs3 = (unsigned short*)alloc((size_t)N * 64 * 2);
  unsigned short* w1h = (unsigned short*)alloc(128 * 128 * 2);
  unsigned short* w1l = (unsigned short*)alloc(128 * 128 * 2);
  unsigned short* w2h = (unsigned short*)alloc(128 * 128 * 2);
  unsigned short* w2l = (unsigned short*)alloc(128 * 128 * 2);
  unsigned short* w3h = (unsigned short*)alloc(64 * 128 * 2);
  unsigned short* w3l = (unsigned short*)alloc(64 * 128 * 2);

  init_cur<<<(B + 255) / 256, 256, 0, stream>>>(cur, B);
  bin_edges<<<BIN_WGS, 256, 0, stream>>>(src, dst, cur, binned, E, B);
  split_w<<<64, 256, 0, stream>>>(W1, w1h, w1l, 128 * 128);
  split_w<<<64, 256, 0, stream>>>(W2, w2h, w2l, 128 * 128);
  split_w<<<32, 256, 0, stream>>>(W3, w3h, w3l, 64 * 128);
  build_buckets<<<B, 256, 0, stream>>>(binned, cur, cols, off2, dinv, N);

  const int gb = (N + 63) / 64;
  const int ab = (N + 3) / 4;

  gemm_xw_mfma<128><<<gb, 256, 0, stream>>>(x, w1h, w1l, dinv, xs1, N);
  agg_gemm<128, true><<<gb, 256, 0, stream>>>(xs1, off2, cols, dinv, b1,
                                              w2h, w2l, xs2, N);
  agg_gemm<64, true><<<gb, 256, 0, stream>>>(xs2, off2, cols, dinv, b2,
                                             w3h, w3l, xs3, N);
  aggregate2<64, false><<<ab, 256, 0, stream>>>(xs3, off2, cols, dinv, b3,
                                                (float*)d_out, N);
}

// Round 10
// 480.807 us; speedup vs baseline: 1.2304x; 1.2304x over previous
//
#include <hip/hip_runtime.h>

// ---------------------------------------------------------------------------
// 3-layer GCN: out = ReLU(Â(ReLU(Â(Â (X W1^T) +b1) W2^T +b2)) W3^T) +b3
// Â = D^{-1/2}(A+I)D^{-1/2}, deg = in-degree + 1 (self loop).
//   xs = dinv[m] * (X @ W^T)   (GEMM epilogue, stored bf16)
//   h  = dinv[d]*(sum xs) + b (+ReLU)  (aggregate, f32)
//
// R9 pm: fusing agg+GEMM throttled the gather to GEMM occupancy (8 waves/CU,
// 1.15 TB/s fill vs 3.75) — reverted. Aggregate is at its structural floor
// (FETCH 188MB ~ 94% of per-XCD dedup bound; time = (FETCH+WRITE)/3.75TB/s).
// R10: GEMM was latency-bound at 2 blk/CU (69.6KB LDS). W planes are the same
// hot 16B/lane addresses for every block -> read B-fragments straight from
// global (L1/L2 resident), no W LDS: 34.8KB LDS -> 4 blk/CU, one sync total.
// split_w merged to one launch.
// ---------------------------------------------------------------------------

#define NPB 256          // nodes per bucket (bucket = dst >> 8)
#define CAP 4672         // edges capacity per bucket region
#define BIN_WGS 512      // workgroups in bin_edges

typedef short bfrag __attribute__((ext_vector_type(8)));       // 8 bf16
typedef float f32x4 __attribute__((ext_vector_type(4)));
typedef unsigned short u16x8 __attribute__((ext_vector_type(8)));

__global__ __launch_bounds__(256) void init_cur(int* __restrict__ cur, int B) {
  int i = blockIdx.x * 256 + threadIdx.x;
  if (i < B) cur[i] = i * CAP;
}

__global__ __launch_bounds__(256) void bin_edges(const int* __restrict__ src,
                                                 const int* __restrict__ dst,
                                                 int* __restrict__ cur,
                                                 int* __restrict__ binned,
                                                 int E, int B) {
  __shared__ int lc[512];
  __shared__ int lbase[512];
  const int t = threadIdx.x;
  const int chunk = (E + BIN_WGS - 1) / BIN_WGS;
  const int e0 = blockIdx.x * chunk;
  const int e1 = min(E, e0 + chunk);

  for (int i = t; i < B; i += 256) lc[i] = 0;
  __syncthreads();
  for (int e = e0 + t; e < e1; e += 256) {
    int d = dst[e];
    atomicAdd(&lc[d >> 8], 1);
  }
  __syncthreads();
  for (int i = t; i < B; i += 256) {
    int c = lc[i];
    lbase[i] = c ? atomicAdd(&cur[i], c) : 0;
    lc[i] = 0;
  }
  __syncthreads();
  for (int e = e0 + t; e < e1; e += 256) {
    int d = dst[e];
    int s = __builtin_nontemporal_load(&src[e]);
    int bk = d >> 8;
    int p = lbase[bk] + atomicAdd(&lc[bk], 1);
    if (p < (bk + 1) * CAP)
      binned[p] = ((d & 255) << 24) | s;
  }
}

__global__ __launch_bounds__(256) void build_buckets(const int* __restrict__ binned,
                                                     const int* __restrict__ cur,
                                                     int* __restrict__ cols,
                                                     int2* __restrict__ off2,
                                                     float* __restrict__ dinv,
                                                     int N) {
  __shared__ int eb[CAP];
  __shared__ int ob[CAP];
  __shared__ int lc[256];
  __shared__ int sc[256];
  const int b = blockIdx.x;
  const int t = threadIdx.x;
  const int base = b * CAP;
  const int cntb = min(cur[b] - base, CAP);

  for (int i = t; i < cntb; i += 256) eb[i] = binned[base + i];
  lc[t] = 0;
  __syncthreads();
  for (int i = t; i < cntb; i += 256)
    atomicAdd(&lc[(unsigned)eb[i] >> 24], 1);
  __syncthreads();
  int myc = lc[t];
  sc[t] = myc;
  __syncthreads();
  for (int d = 1; d < 256; d <<= 1) {
    int a = (t >= d) ? sc[t - d] : 0;
    __syncthreads();
    sc[t] += a;
    __syncthreads();
  }
  int excl = sc[t] - myc;
  int node = b * NPB + t;
  if (node < N) {
    off2[node] = make_int2(base + excl, base + excl + myc);
    dinv[node] = rsqrtf((float)(myc + 1));
  }
  lc[t] = excl;
  __syncthreads();
  for (int i = t; i < cntb; i += 256) {
    int e = eb[i];
    int p = atomicAdd(&lc[(unsigned)e >> 24], 1);
    ob[p] = e & 0xFFFFFF;
  }
  __syncthreads();
  for (int i = t; i < cntb; i += 256) cols[base + i] = ob[i];
}

// ---------------------------------------------------------------------------
__device__ inline unsigned short bf16rne(float x) {
  unsigned u = __float_as_uint(x);
  return (unsigned short)((u + 0x7FFFu + ((u >> 16) & 1u)) >> 16);
}
__device__ inline float bf16lo(unsigned q) { return __uint_as_float(q << 16); }
__device__ inline float bf16hi(unsigned q) { return __uint_as_float(q & 0xFFFF0000u); }

// All three W -> hi/lo bf16 plane splits in ONE launch (R10)
__global__ __launch_bounds__(256) void split_w3(const float* __restrict__ W1,
                                                const float* __restrict__ W2,
                                                const float* __restrict__ W3,
                                                unsigned short* __restrict__ w1h,
                                                unsigned short* __restrict__ w1l,
                                                unsigned short* __restrict__ w2h,
                                                unsigned short* __restrict__ w2l,
                                                unsigned short* __restrict__ w3h,
                                                unsigned short* __restrict__ w3l) {
  int i = blockIdx.x * 256 + threadIdx.x;
  const float* W;
  unsigned short *hi, *lo;
  int j;
  if (i < 16384) {
    W = W1; hi = w1h; lo = w1l; j = i;
  } else if (i < 32768) {
    W = W2; hi = w2h; lo = w2l; j = i - 16384;
  } else if (i < 40960) {
    W = W3; hi = w3h; lo = w3l; j = i - 32768;
  } else {
    return;
  }
  float v = W[j];
  unsigned short h = bf16rne(v);
  hi[j] = h;
  lo[j] = bf16rne(v - __uint_as_float((unsigned)h << 16));
}

// ---------------------------------------------------------------------------
// MFMA split-bf16 GEMM: Y[m][c] = bf16( dinv[m] * dot(X[m][:], W[c][:]) )
// X staged f32 -> hi/lo bf16 LDS planes (34.8KB -> 4 blk/CU). B-fragments
// (W planes) read directly from global: same addresses for every block =>
// L1/L2 hot; one __syncthreads total; split-bf16 (xh*wh + xl*wh + xh*wl).
// ---------------------------------------------------------------------------
#define LDP 136  // padded LDS row stride (bf16 elems): 2-way bank alias only
template <int OUTC>
__global__ __launch_bounds__(256) void gemm_xw_mfma(const float* __restrict__ X,
                                                    const unsigned short* __restrict__ Whg,
                                                    const unsigned short* __restrict__ Wlg,
                                                    const float* __restrict__ dinv,
                                                    unsigned short* __restrict__ Y,
                                                    int M) {
  __shared__ unsigned short Xhi[64 * LDP], Xlo[64 * LDP];
  const int tid = threadIdx.x;
  const int m_base = blockIdx.x * 64;

  // stage X tile: 64 rows x 128 f32 -> hi/lo bf16 planes
  for (int idx = tid; idx < 64 * 16; idx += 256) {
    int r = idx >> 4, g = idx & 15;
    int m = m_base + r;
    float4 v0 = make_float4(0.f, 0.f, 0.f, 0.f), v1 = v0;
    if (m < M) {
      const float4* px = (const float4*)(X + (size_t)m * 128 + g * 8);
      v0 = px[0];
      v1 = px[1];
    }
    float vv[8] = {v0.x, v0.y, v0.z, v0.w, v1.x, v1.y, v1.z, v1.w};
    u16x8 hv, lv;
#pragma unroll
    for (int j = 0; j < 8; ++j) {
      unsigned short h = bf16rne(vv[j]);
      float res = vv[j] - __uint_as_float((unsigned)h << 16);
      hv[j] = h;
      lv[j] = bf16rne(res);
    }
    *(u16x8*)(Xhi + r * LDP + g * 8) = hv;
    *(u16x8*)(Xlo + r * LDP + g * 8) = lv;
  }
  __syncthreads();

  const int lane = tid & 63;
  const int wv = tid >> 6;
  const int col_l = lane & 15;
  const int quad = lane >> 4;
  const int aBase = (wv * 16 + col_l) * LDP + quad * 8;

  for (int cc = 0; cc < OUTC; cc += 64) {
    f32x4 acc[4] = {{0.f, 0.f, 0.f, 0.f},
                    {0.f, 0.f, 0.f, 0.f},
                    {0.f, 0.f, 0.f, 0.f},
                    {0.f, 0.f, 0.f, 0.f}};
#pragma unroll
    for (int ks = 0; ks < 4; ++ks) {
      int ao = aBase + ks * 32;
      bfrag aHi = *(const bfrag*)(Xhi + ao);
      bfrag aLo = *(const bfrag*)(Xlo + ao);
#pragma unroll
      for (int t = 0; t < 4; ++t) {
        size_t wo = (size_t)(cc + t * 16 + col_l) * 128 + ks * 32 + quad * 8;
        bfrag bHi = *(const bfrag*)(Whg + wo);
        bfrag bLo = *(const bfrag*)(Wlg + wo);
        acc[t] = __builtin_amdgcn_mfma_f32_16x16x32_bf16(aHi, bHi, acc[t], 0, 0, 0);
        acc[t] = __builtin_amdgcn_mfma_f32_16x16x32_bf16(aLo, bHi, acc[t], 0, 0, 0);
        acc[t] = __builtin_amdgcn_mfma_f32_16x16x32_bf16(aHi, bLo, acc[t], 0, 0, 0);
      }
    }

#pragma unroll
    for (int r = 0; r < 4; ++r) {
      int row = m_base + wv * 16 + quad * 4 + r;
      if (row < M) {
        float s = dinv[row];
#pragma unroll
        for (int t = 0; t < 4; ++t) {
          unsigned short h = bf16rne(acc[t][r] * s);
          Y[(size_t)row * OUTC + cc + t * 16 + col_l] = h;
        }
      }
    }
  }
}

// ---------------------------------------------------------------------------
// Aggregate: one wave per dst node. lane = (eg, cg); 16B uint4 gathers, 4
// edges in flight; butterfly shfl_xor reduce; f32 out (nt store).
// ---------------------------------------------------------------------------
template <int C, bool RELU>
__global__ __launch_bounds__(256) void aggregate2(const unsigned short* __restrict__ xs,
                                                  const int2* __restrict__ off2,
                                                  const int* __restrict__ cols,
                                                  const float* __restrict__ dinv,
                                                  const float* __restrict__ bias,
                                                  float* __restrict__ out, int N) {
  constexpr int CG = C / 8;
  constexpr int EG = 64 / CG;
  int wid = (int)((blockIdx.x * blockDim.x + threadIdx.x) >> 6);
  int lane = threadIdx.x & 63;
  if (wid >= N) return;
  const int eg = lane / CG;
  const int cg = lane % CG;

  float acc[8] = {0.f, 0.f, 0.f, 0.f, 0.f, 0.f, 0.f, 0.f};
  if (eg == 0) {
    uint4 d = *(const uint4*)(xs + (size_t)wid * C + cg * 8);
    acc[0] = bf16lo(d.x); acc[1] = bf16hi(d.x);
    acc[2] = bf16lo(d.y); acc[3] = bf16hi(d.y);
    acc[4] = bf16lo(d.z); acc[5] = bf16hi(d.z);
    acc[6] = bf16lo(d.w); acc[7] = bf16hi(d.w);
  }

  int2 oo = off2[wid];
  int ebase = oo.x;
  const int eend = oo.y;
  while (ebase < eend) {
    int cnt = eend - ebase;
    if (cnt > 64) cnt = 64;
    int col = (lane < cnt) ? __builtin_nontemporal_load(&cols[ebase + lane]) : 0;
    const int c1 = cnt - 1;
    for (int j = 0; j < cnt; j += 4 * EG) {
      int i0 = j + eg, i1 = i0 + EG, i2 = i1 + EG, i3 = i2 + EG;
      int s0 = __shfl(col, min(i0, c1));
      int s1 = __shfl(col, min(i1, c1));
      int s2 = __shfl(col, min(i2, c1));
      int s3 = __shfl(col, min(i3, c1));
      uint4 d0 = *(const uint4*)(xs + (size_t)s0 * C + cg * 8);
      uint4 d1 = *(const uint4*)(xs + (size_t)s1 * C + cg * 8);
      uint4 d2 = *(const uint4*)(xs + (size_t)s2 * C + cg * 8);
      uint4 d3 = *(const uint4*)(xs + (size_t)s3 * C + cg * 8);
      if (i0 < cnt) {
        acc[0] += bf16lo(d0.x); acc[1] += bf16hi(d0.x);
        acc[2] += bf16lo(d0.y); acc[3] += bf16hi(d0.y);
        acc[4] += bf16lo(d0.z); acc[5] += bf16hi(d0.z);
        acc[6] += bf16lo(d0.w); acc[7] += bf16hi(d0.w);
      }
      if (i1 < cnt) {
        acc[0] += bf16lo(d1.x); acc[1] += bf16hi(d1.x);
        acc[2] += bf16lo(d1.y); acc[3] += bf16hi(d1.y);
        acc[4] += bf16lo(d1.z); acc[5] += bf16hi(d1.z);
        acc[6] += bf16lo(d1.w); acc[7] += bf16hi(d1.w);
      }
      if (i2 < cnt) {
        acc[0] += bf16lo(d2.x); acc[1] += bf16hi(d2.x);
        acc[2] += bf16lo(d2.y); acc[3] += bf16hi(d2.y);
        acc[4] += bf16lo(d2.z); acc[5] += bf16hi(d2.z);
        acc[6] += bf16lo(d2.w); acc[7] += bf16hi(d2.w);
      }
      if (i3 < cnt) {
        acc[0] += bf16lo(d3.x); acc[1] += bf16hi(d3.x);
        acc[2] += bf16lo(d3.y); acc[3] += bf16hi(d3.y);
        acc[4] += bf16lo(d3.z); acc[5] += bf16hi(d3.z);
        acc[6] += bf16lo(d3.w); acc[7] += bf16hi(d3.w);
      }
    }
    ebase += cnt;
  }

#pragma unroll
  for (int m = CG; m < 64; m <<= 1) {
#pragma unroll
    for (int q = 0; q < 8; ++q) acc[q] += __shfl_xor(acc[q], m);
  }

  if (eg == 0) {
    float dd = dinv[wid];
    const float4 bA = *(const float4*)(bias + cg * 8);
    const float4 bB = *(const float4*)(bias + cg * 8 + 4);
    f32x4 oA, oB;
    oA[0] = acc[0] * dd + bA.x; oA[1] = acc[1] * dd + bA.y;
    oA[2] = acc[2] * dd + bA.z; oA[3] = acc[3] * dd + bA.w;
    oB[0] = acc[4] * dd + bB.x; oB[1] = acc[5] * dd + bB.y;
    oB[2] = acc[6] * dd + bB.z; oB[3] = acc[7] * dd + bB.w;
    if (RELU) {
#pragma unroll
      for (int q = 0; q < 4; ++q) {
        oA[q] = fmaxf(oA[q], 0.f);
        oB[q] = fmaxf(oB[q], 0.f);
      }
    }
    __builtin_nontemporal_store(oA, (f32x4*)(out + (size_t)wid * C + cg * 8));
    __builtin_nontemporal_store(oB, (f32x4*)(out + (size_t)wid * C + cg * 8 + 4));
  }
}

// ---------------------------------------------------------------------------

extern "C" void kernel_launch(void* const* d_in, const int* in_sizes, int n_in,
                              void* d_out, int out_size, void* d_ws, size_t ws_size,
                              hipStream_t stream) {
  const float* x  = (const float*)d_in[0];
  const int*   ei = (const int*)d_in[1];
  const float* W1 = (const float*)d_in[2];
  const float* b1 = (const float*)d_in[3];
  const float* W2 = (const float*)d_in[4];
  const float* b2 = (const float*)d_in[5];
  const float* W3 = (const float*)d_in[6];
  const float* b3 = (const float*)d_in[7];

  const int N = in_sizes[0] / 128;
  const int E = in_sizes[1] / 2;
  const int* src = ei;
  const int* dst = ei + E;
  const int B = (N + NPB - 1) / NPB;

  char* w = (char*)d_ws;
  size_t p = 0;
  auto alloc = [&](size_t bytes) -> void* {
    void* r = w + p;
    p = (p + bytes + 255) & ~(size_t)255;
    return r;
  };
  float*    dinv   = (float*)alloc((size_t)N * 4);
  int2*     off2   = (int2*)alloc((size_t)N * 8);
  int*      cur    = (int*)alloc((size_t)B * 4);
  int*      binned = (int*)alloc((size_t)B * CAP * 4);
  int*      cols   = (int*)alloc((size_t)B * CAP * 4);
  unsigned short* xsb = (unsigned short*)alloc((size_t)N * 128 * 2);  // bf16 xs
  float*    bufB   = (float*)alloc((size_t)N * 128 * 4);              // f32 acts
  unsigned short* w1h = (unsigned short*)alloc(128 * 128 * 2);
  unsigned short* w1l = (unsigned short*)alloc(128 * 128 * 2);
  unsigned short* w2h = (unsigned short*)alloc(128 * 128 * 2);
  unsigned short* w2l = (unsigned short*)alloc(128 * 128 * 2);
  unsigned short* w3h = (unsigned short*)alloc(64 * 128 * 2);
  unsigned short* w3l = (unsigned short*)alloc(64 * 128 * 2);

  init_cur<<<(B + 255) / 256, 256, 0, stream>>>(cur, B);
  bin_edges<<<BIN_WGS, 256, 0, stream>>>(src, dst, cur, binned, E, B);
  split_w3<<<160, 256, 0, stream>>>(W1, W2, W3, w1h, w1l, w2h, w2l, w3h, w3l);
  build_buckets<<<B, 256, 0, stream>>>(binned, cur, cols, off2, dinv, N);

  const int gb = (N + 63) / 64;
  const int ab = (N + 3) / 4;

  gemm_xw_mfma<128><<<gb, 256, 0, stream>>>(x, w1h, w1l, dinv, xsb, N);
  aggregate2<128, true><<<ab, 256, 0, stream>>>(xsb, off2, cols, dinv, b1, bufB, N);
  gemm_xw_mfma<128><<<gb, 256, 0, stream>>>(bufB, w2h, w2l, dinv, xsb, N);
  aggregate2<128, true><<<ab, 256, 0, stream>>>(xsb, off2, cols, dinv, b2, bufB, N);
  gemm_xw_mfma<64><<<gb, 256, 0, stream>>>(bufB, w3h, w3l, dinv, xsb, N);
  aggregate2<64, false><<<ab, 256, 0, stream>>>(xsb, off2, cols, dinv, b3,
                                                (float*)d_out, N);
}

// Round 11
// 422.189 us; speedup vs baseline: 1.4013x; 1.1388x over previous
//
#include <hip/hip_runtime.h>

// ---------------------------------------------------------------------------
// 3-layer GCN: out = ReLU(Â(ReLU(Â(Â (X W1^T) +b1) W2^T +b2)) W3^T) +b3
// Â = D^{-1/2}(A+I)D^{-1/2}, deg = in-degree + 1 (self loop).
// Dtype plan: xs (GEMM out) = bf16 plane [N][C]; h (agg out) = bf16 hi/lo
// planes (split-bf16 ~ f32); GEMM = split-bf16 MFMA (xh*wh + xl*wh + xh*wl).
//
// R10 pm: W-from-global put L2 latency inside the MFMA loop (W 64KB > L1,
// 16 waves streaming it) -> 70us, MfmaUtil 5%. R8's W-in-LDS was right; the
// waste was X-in-LDS (zero cross-block reuse) + per-chunk W restage.
// R11: activations live as bf16 hi/lo planes in GLOBAL (aggregate epilogue
// writes planes; split_x prepass for layer 1 — identical arithmetic to the
// old in-GEMM split => absmax unchanged). GEMM v3: W chunk in LDS once
// (34.8KB -> 4 blk/CU, one sync), cc-chunk in blockIdx, A-fragments direct
// 16B global loads (few, independent, prefetched -> hidable).
// ---------------------------------------------------------------------------

#define NPB 256          // nodes per bucket (bucket = dst >> 8)
#define CAP 4672         // edges capacity per bucket region
#define BIN_WGS 512      // workgroups in bin_edges

typedef short bfrag __attribute__((ext_vector_type(8)));       // 8 bf16
typedef float f32x4 __attribute__((ext_vector_type(4)));
typedef unsigned short u16x8 __attribute__((ext_vector_type(8)));

__global__ __launch_bounds__(256) void init_cur(int* __restrict__ cur, int B) {
  int i = blockIdx.x * 256 + threadIdx.x;
  if (i < B) cur[i] = i * CAP;
}

__global__ __launch_bounds__(256) void bin_edges(const int* __restrict__ src,
                                                 const int* __restrict__ dst,
                                                 int* __restrict__ cur,
                                                 int* __restrict__ binned,
                                                 int E, int B) {
  __shared__ int lc[512];
  __shared__ int lbase[512];
  const int t = threadIdx.x;
  const int chunk = (E + BIN_WGS - 1) / BIN_WGS;
  const int e0 = blockIdx.x * chunk;
  const int e1 = min(E, e0 + chunk);

  for (int i = t; i < B; i += 256) lc[i] = 0;
  __syncthreads();
  for (int e = e0 + t; e < e1; e += 256) {
    int d = dst[e];
    atomicAdd(&lc[d >> 8], 1);
  }
  __syncthreads();
  for (int i = t; i < B; i += 256) {
    int c = lc[i];
    lbase[i] = c ? atomicAdd(&cur[i], c) : 0;
    lc[i] = 0;
  }
  __syncthreads();
  for (int e = e0 + t; e < e1; e += 256) {
    int d = dst[e];
    int s = __builtin_nontemporal_load(&src[e]);
    int bk = d >> 8;
    int p = lbase[bk] + atomicAdd(&lc[bk], 1);
    if (p < (bk + 1) * CAP)
      binned[p] = ((d & 255) << 24) | s;
  }
}

__global__ __launch_bounds__(256) void build_buckets(const int* __restrict__ binned,
                                                     const int* __restrict__ cur,
                                                     int* __restrict__ cols,
                                                     int2* __restrict__ off2,
                                                     float* __restrict__ dinv,
                                                     int N) {
  __shared__ int eb[CAP];
  __shared__ int ob[CAP];
  __shared__ int lc[256];
  __shared__ int sc[256];
  const int b = blockIdx.x;
  const int t = threadIdx.x;
  const int base = b * CAP;
  const int cntb = min(cur[b] - base, CAP);

  for (int i = t; i < cntb; i += 256) eb[i] = binned[base + i];
  lc[t] = 0;
  __syncthreads();
  for (int i = t; i < cntb; i += 256)
    atomicAdd(&lc[(unsigned)eb[i] >> 24], 1);
  __syncthreads();
  int myc = lc[t];
  sc[t] = myc;
  __syncthreads();
  for (int d = 1; d < 256; d <<= 1) {
    int a = (t >= d) ? sc[t - d] : 0;
    __syncthreads();
    sc[t] += a;
    __syncthreads();
  }
  int excl = sc[t] - myc;
  int node = b * NPB + t;
  if (node < N) {
    off2[node] = make_int2(base + excl, base + excl + myc);
    dinv[node] = rsqrtf((float)(myc + 1));
  }
  lc[t] = excl;
  __syncthreads();
  for (int i = t; i < cntb; i += 256) {
    int e = eb[i];
    int p = atomicAdd(&lc[(unsigned)e >> 24], 1);
    ob[p] = e & 0xFFFFFF;
  }
  __syncthreads();
  for (int i = t; i < cntb; i += 256) cols[base + i] = ob[i];
}

// ---------------------------------------------------------------------------
__device__ inline unsigned short bf16rne(float x) {
  unsigned u = __float_as_uint(x);
  return (unsigned short)((u + 0x7FFFu + ((u >> 16) & 1u)) >> 16);
}
__device__ inline float bf16lo(unsigned q) { return __uint_as_float(q << 16); }
__device__ inline float bf16hi(unsigned q) { return __uint_as_float(q & 0xFFFF0000u); }

// All three W -> hi/lo bf16 plane splits in ONE launch
__global__ __launch_bounds__(256) void split_w3(const float* __restrict__ W1,
                                                const float* __restrict__ W2,
                                                const float* __restrict__ W3,
                                                unsigned short* __restrict__ w1h,
                                                unsigned short* __restrict__ w1l,
                                                unsigned short* __restrict__ w2h,
                                                unsigned short* __restrict__ w2l,
                                                unsigned short* __restrict__ w3h,
                                                unsigned short* __restrict__ w3l) {
  int i = blockIdx.x * 256 + threadIdx.x;
  const float* W;
  unsigned short *hi, *lo;
  int j;
  if (i < 16384) {
    W = W1; hi = w1h; lo = w1l; j = i;
  } else if (i < 32768) {
    W = W2; hi = w2h; lo = w2l; j = i - 16384;
  } else if (i < 40960) {
    W = W3; hi = w3h; lo = w3l; j = i - 32768;
  } else {
    return;
  }
  float v = W[j];
  unsigned short h = bf16rne(v);
  hi[j] = h;
  lo[j] = bf16rne(v - __uint_as_float((unsigned)h << 16));
}

// x f32 [N][128] -> hi/lo bf16 planes (thread = 8 contiguous floats)
__global__ __launch_bounds__(256) void split_x(const float* __restrict__ X,
                                               unsigned short* __restrict__ xh,
                                               unsigned short* __restrict__ xl,
                                               int total8) {
  int i = blockIdx.x * 256 + threadIdx.x;
  if (i >= total8) return;
  const float4* px = (const float4*)(X + (size_t)i * 8);
  float4 v0 = px[0], v1 = px[1];
  float vv[8] = {v0.x, v0.y, v0.z, v0.w, v1.x, v1.y, v1.z, v1.w};
  u16x8 hv, lv;
#pragma unroll
  for (int j = 0; j < 8; ++j) {
    unsigned short h = bf16rne(vv[j]);
    hv[j] = h;
    lv[j] = bf16rne(vv[j] - __uint_as_float((unsigned)h << 16));
  }
  __builtin_nontemporal_store(hv, (u16x8*)(xh + (size_t)i * 8));
  __builtin_nontemporal_store(lv, (u16x8*)(xl + (size_t)i * 8));
}

// ---------------------------------------------------------------------------
// GEMM v3: Y[m][c] = bf16( dinv[m] * dot(X[m][:], W[c][:]) ), K=128.
// X as bf16 hi/lo planes in global (A-fragments: per-lane 16B direct loads,
// prefetched). W 64-row chunk staged once into LDS (34.8KB, 4 blk/CU), one
// sync. blockIdx.x = m_tile * CHUNKS + cc_chunk.
// ---------------------------------------------------------------------------
#define LDP 136  // padded LDS row stride (bf16): breaks 16-way bank conflict
template <int OUTC>
__global__ __launch_bounds__(256) void gemm_planes(const unsigned short* __restrict__ Xh,
                                                   const unsigned short* __restrict__ Xl,
                                                   const unsigned short* __restrict__ Whg,
                                                   const unsigned short* __restrict__ Wlg,
                                                   const float* __restrict__ dinv,
                                                   unsigned short* __restrict__ Y,
                                                   int M) {
  constexpr int CHUNKS = OUTC / 64;
  __shared__ unsigned short Whi[64 * LDP], Wlo[64 * LDP];
  const int tid = threadIdx.x;
  const int bx = blockIdx.x;
  const int m_base = (bx / CHUNKS) * 64;
  const int cc = (bx % CHUNKS) * 64;

  // stage W chunk (64 rows x 128) hi/lo planes
  for (int idx = tid; idx < 64 * 16; idx += 256) {
    int r = idx >> 4, g = idx & 15;
    *(u16x8*)(Whi + r * LDP + g * 8) =
        *(const u16x8*)(Whg + (size_t)(cc + r) * 128 + g * 8);
    *(u16x8*)(Wlo + r * LDP + g * 8) =
        *(const u16x8*)(Wlg + (size_t)(cc + r) * 128 + g * 8);
  }
  __syncthreads();

  const int lane = tid & 63;
  const int wv = tid >> 6;
  const int col_l = lane & 15;   // A-row within wave tile / D col
  const int quad = lane >> 4;    // k-quad / D row group
  const size_t arow = (size_t)min(m_base + wv * 16 + col_l, M - 1) * 128;
  const int bBase = col_l * LDP + quad * 8;

  // prefetch all A fragments (8 independent 16B loads)
  bfrag aH[4], aL[4];
#pragma unroll
  for (int ks = 0; ks < 4; ++ks) {
    aH[ks] = *(const bfrag*)(Xh + arow + ks * 32 + quad * 8);
    aL[ks] = *(const bfrag*)(Xl + arow + ks * 32 + quad * 8);
  }

  f32x4 acc[4] = {{0.f, 0.f, 0.f, 0.f},
                  {0.f, 0.f, 0.f, 0.f},
                  {0.f, 0.f, 0.f, 0.f},
                  {0.f, 0.f, 0.f, 0.f}};
#pragma unroll
  for (int ks = 0; ks < 4; ++ks) {
#pragma unroll
    for (int t = 0; t < 4; ++t) {
      int bo = bBase + t * 16 * LDP + ks * 32;
      bfrag bHi = *(const bfrag*)(Whi + bo);
      bfrag bLo = *(const bfrag*)(Wlo + bo);
      acc[t] = __builtin_amdgcn_mfma_f32_16x16x32_bf16(aH[ks], bHi, acc[t], 0, 0, 0);
      acc[t] = __builtin_amdgcn_mfma_f32_16x16x32_bf16(aL[ks], bHi, acc[t], 0, 0, 0);
      acc[t] = __builtin_amdgcn_mfma_f32_16x16x32_bf16(aH[ks], bLo, acc[t], 0, 0, 0);
    }
  }

#pragma unroll
  for (int r = 0; r < 4; ++r) {
    int row = m_base + wv * 16 + quad * 4 + r;
    if (row < M) {
      float s = dinv[row];
#pragma unroll
      for (int t = 0; t < 4; ++t) {
        unsigned short h = bf16rne(acc[t][r] * s);
        Y[(size_t)row * OUTC + cc + t * 16 + col_l] = h;
      }
    }
  }
}

// ---------------------------------------------------------------------------
// Aggregate: one wave per dst node; xs bf16 [N][C]; 16B uint4 gathers, 4
// edges in flight; butterfly shfl_xor. Epilogue: SPLIT ? bf16 hi/lo planes
// (next GEMM input) : f32 (final output).
// ---------------------------------------------------------------------------
template <int C, bool RELU, bool SPLIT>
__global__ __launch_bounds__(256) void aggregate3(const unsigned short* __restrict__ xs,
                                                  const int2* __restrict__ off2,
                                                  const int* __restrict__ cols,
                                                  const float* __restrict__ dinv,
                                                  const float* __restrict__ bias,
                                                  float* __restrict__ outf,
                                                  unsigned short* __restrict__ oh,
                                                  unsigned short* __restrict__ ol,
                                                  int N) {
  constexpr int CG = C / 8;
  constexpr int EG = 64 / CG;
  int wid = (int)((blockIdx.x * blockDim.x + threadIdx.x) >> 6);
  int lane = threadIdx.x & 63;
  if (wid >= N) return;
  const int eg = lane / CG;
  const int cg = lane % CG;

  float acc[8] = {0.f, 0.f, 0.f, 0.f, 0.f, 0.f, 0.f, 0.f};
  if (eg == 0) {
    uint4 d = *(const uint4*)(xs + (size_t)wid * C + cg * 8);
    acc[0] = bf16lo(d.x); acc[1] = bf16hi(d.x);
    acc[2] = bf16lo(d.y); acc[3] = bf16hi(d.y);
    acc[4] = bf16lo(d.z); acc[5] = bf16hi(d.z);
    acc[6] = bf16lo(d.w); acc[7] = bf16hi(d.w);
  }

  int2 oo = off2[wid];
  int ebase = oo.x;
  const int eend = oo.y;
  while (ebase < eend) {
    int cnt = eend - ebase;
    if (cnt > 64) cnt = 64;
    int col = (lane < cnt) ? __builtin_nontemporal_load(&cols[ebase + lane]) : 0;
    const int c1 = cnt - 1;
    for (int j = 0; j < cnt; j += 4 * EG) {
      int i0 = j + eg, i1 = i0 + EG, i2 = i1 + EG, i3 = i2 + EG;
      int s0 = __shfl(col, min(i0, c1));
      int s1 = __shfl(col, min(i1, c1));
      int s2 = __shfl(col, min(i2, c1));
      int s3 = __shfl(col, min(i3, c1));
      uint4 d0 = *(const uint4*)(xs + (size_t)s0 * C + cg * 8);
      uint4 d1 = *(const uint4*)(xs + (size_t)s1 * C + cg * 8);
      uint4 d2 = *(const uint4*)(xs + (size_t)s2 * C + cg * 8);
      uint4 d3 = *(const uint4*)(xs + (size_t)s3 * C + cg * 8);
      if (i0 < cnt) {
        acc[0] += bf16lo(d0.x); acc[1] += bf16hi(d0.x);
        acc[2] += bf16lo(d0.y); acc[3] += bf16hi(d0.y);
        acc[4] += bf16lo(d0.z); acc[5] += bf16hi(d0.z);
        acc[6] += bf16lo(d0.w); acc[7] += bf16hi(d0.w);
      }
      if (i1 < cnt) {
        acc[0] += bf16lo(d1.x); acc[1] += bf16hi(d1.x);
        acc[2] += bf16lo(d1.y); acc[3] += bf16hi(d1.y);
        acc[4] += bf16lo(d1.z); acc[5] += bf16hi(d1.z);
        acc[6] += bf16lo(d1.w); acc[7] += bf16hi(d1.w);
      }
      if (i2 < cnt) {
        acc[0] += bf16lo(d2.x); acc[1] += bf16hi(d2.x);
        acc[2] += bf16lo(d2.y); acc[3] += bf16hi(d2.y);
        acc[4] += bf16lo(d2.z); acc[5] += bf16hi(d2.z);
        acc[6] += bf16lo(d2.w); acc[7] += bf16hi(d2.w);
      }
      if (i3 < cnt) {
        acc[0] += bf16lo(d3.x); acc[1] += bf16hi(d3.x);
        acc[2] += bf16lo(d3.y); acc[3] += bf16hi(d3.y);
        acc[4] += bf16lo(d3.z); acc[5] += bf16hi(d3.z);
        acc[6] += bf16lo(d3.w); acc[7] += bf16hi(d3.w);
      }
    }
    ebase += cnt;
  }

#pragma unroll
  for (int m = CG; m < 64; m <<= 1) {
#pragma unroll
    for (int q = 0; q < 8; ++q) acc[q] += __shfl_xor(acc[q], m);
  }

  if (eg == 0) {
    float dd = dinv[wid];
    const float4 bA = *(const float4*)(bias + cg * 8);
    const float4 bB = *(const float4*)(bias + cg * 8 + 4);
    float h[8];
    h[0] = acc[0] * dd + bA.x; h[1] = acc[1] * dd + bA.y;
    h[2] = acc[2] * dd + bA.z; h[3] = acc[3] * dd + bA.w;
    h[4] = acc[4] * dd + bB.x; h[5] = acc[5] * dd + bB.y;
    h[6] = acc[6] * dd + bB.z; h[7] = acc[7] * dd + bB.w;
    if (RELU) {
#pragma unroll
      for (int q = 0; q < 8; ++q) h[q] = fmaxf(h[q], 0.f);
    }
    if (SPLIT) {
      u16x8 hv, lv;
#pragma unroll
      for (int q = 0; q < 8; ++q) {
        unsigned short hb = bf16rne(h[q]);
        hv[q] = hb;
        lv[q] = bf16rne(h[q] - __uint_as_float((unsigned)hb << 16));
      }
      __builtin_nontemporal_store(hv, (u16x8*)(oh + (size_t)wid * C + cg * 8));
      __builtin_nontemporal_store(lv, (u16x8*)(ol + (size_t)wid * C + cg * 8));
    } else {
      f32x4 oA = {h[0], h[1], h[2], h[3]};
      f32x4 oB = {h[4], h[5], h[6], h[7]};
      __builtin_nontemporal_store(oA, (f32x4*)(outf + (size_t)wid * C + cg * 8));
      __builtin_nontemporal_store(oB, (f32x4*)(outf + (size_t)wid * C + cg * 8 + 4));
    }
  }
}

// ---------------------------------------------------------------------------

extern "C" void kernel_launch(void* const* d_in, const int* in_sizes, int n_in,
                              void* d_out, int out_size, void* d_ws, size_t ws_size,
                              hipStream_t stream) {
  const float* x  = (const float*)d_in[0];
  const int*   ei = (const int*)d_in[1];
  const float* W1 = (const float*)d_in[2];
  const float* b1 = (const float*)d_in[3];
  const float* W2 = (const float*)d_in[4];
  const float* b2 = (const float*)d_in[5];
  const float* W3 = (const float*)d_in[6];
  const float* b3 = (const float*)d_in[7];

  const int N = in_sizes[0] / 128;
  const int E = in_sizes[1] / 2;
  const int* src = ei;
  const int* dst = ei + E;
  const int B = (N + NPB - 1) / NPB;

  char* w = (char*)d_ws;
  size_t p = 0;
  auto alloc = [&](size_t bytes) -> void* {
    void* r = w + p;
    p = (p + bytes + 255) & ~(size_t)255;
    return r;
  };
  float*    dinv   = (float*)alloc((size_t)N * 4);
  int2*     off2   = (int2*)alloc((size_t)N * 8);
  int*      cur    = (int*)alloc((size_t)B * 4);
  int*      binned = (int*)alloc((size_t)B * CAP * 4);
  int*      cols   = (int*)alloc((size_t)B * CAP * 4);
  unsigned short* xsb = (unsigned short*)alloc((size_t)N * 128 * 2);  // GEMM out
  unsigned short* hh  = (unsigned short*)alloc((size_t)N * 128 * 2);  // h hi plane
  unsigned short* hl  = (unsigned short*)alloc((size_t)N * 128 * 2);  // h lo plane
  unsigned short* w1h = (unsigned short*)alloc(128 * 128 * 2);
  unsigned short* w1l = (unsigned short*)alloc(128 * 128 * 2);
  unsigned short* w2h = (unsigned short*)alloc(128 * 128 * 2);
  unsigned short* w2l = (unsigned short*)alloc(128 * 128 * 2);
  unsigned short* w3h = (unsigned short*)alloc(64 * 128 * 2);
  unsigned short* w3l = (unsigned short*)alloc(64 * 128 * 2);
  unsigned short* xh  = (unsigned short*)alloc((size_t)N * 128 * 2);  // x hi
  unsigned short* xl  = (unsigned short*)alloc((size_t)N * 128 * 2);  // x lo

  init_cur<<<(B + 255) / 256, 256, 0, stream>>>(cur, B);
  bin_edges<<<BIN_WGS, 256, 0, stream>>>(src, dst, cur, binned, E, B);
  split_w3<<<160, 256, 0, stream>>>(W1, W2, W3, w1h, w1l, w2h, w2l, w3h, w3l);
  split_x<<<(N * 16 + 255) / 256, 256, 0, stream>>>(x, xh, xl, N * 16);
  build_buckets<<<B, 256, 0, stream>>>(binned, cur, cols, off2, dinv, N);

  const int gb = (N + 63) / 64;
  const int ab = (N + 3) / 4;

  gemm_planes<128><<<gb * 2, 256, 0, stream>>>(xh, xl, w1h, w1l, dinv, xsb, N);
  aggregate3<128, true, true><<<ab, 256, 0, stream>>>(xsb, off2, cols, dinv, b1,
                                                      nullptr, hh, hl, N);
  gemm_planes<128><<<gb * 2, 256, 0, stream>>>(hh, hl, w2h, w2l, dinv, xsb, N);
  aggregate3<128, true, true><<<ab, 256, 0, stream>>>(xsb, off2, cols, dinv, b2,
                                                      nullptr, hh, hl, N);
  gemm_planes<64><<<gb, 256, 0, stream>>>(hh, hl, w3h, w3l, dinv, xsb, N);
  aggregate3<64, false, false><<<ab, 256, 0, stream>>>(xsb, off2, cols, dinv, b3,
                                                       (float*)d_out, nullptr,
                                                       nullptr, N);
}